// Round 9
// baseline (484.087 us; speedup 1.0000x reference)
//
#include <hip/hip_runtime.h>
#include <stdint.h>

#define B 8192
#define T 512
#define K 24

__device__ __forceinline__ float max3f(float a, float b, float c) {
    return fmaxf(fmaxf(a, b), c);   // fuses to v_max3_f32
}

// ---------------------------------------------------------------------------
// Forward Viterbi, VALUE-ONLY. One tag column per lane; 32-lane group per
// batch (lanes 24..31 idle); 2 batches/wave; 256-thr blocks -> 4096 waves
// (4/SIMD). Alpha exchange via LDS within the wave (in-order DS pipe, no
// barriers). Max via v_max3 trees (order-free exact). Alpha_t streams into
// d_out[b][t][:]; backtrack recomputes exact argmax and overwrites.
// ---------------------------------------------------------------------------
__global__ __launch_bounds__(256) __attribute__((amdgpu_waves_per_eu(4, 4)))
void crf_forward(const float* __restrict__ inp,    // [B, T, K]
                 const float* __restrict__ trans,  // [K, K] (prev i -> cur j)
                 float* __restrict__ out)          // [B, T, K] <- alpha
{
    __shared__ float alpha[2][4][2][32];   // [buf][wave][group][tag(+pad)]

    const int tid  = threadIdx.x;
    const int wv   = tid >> 6;
    const int half = (tid >> 5) & 1;       // batch group within wave
    const int j    = tid & 31;             // tag column (24..31 idle)
    const int b    = blockIdx.x * 8 + wv * 2 + half;

    const bool act = (j < K);
    const int  jo  = act ? j : (K - 1);    // clamped (in-bounds) lane offset

    float tc[K];                           // transition column j
#pragma unroll
    for (int i = 0; i < K; ++i) tc[i] = trans[i * K + jo];

    const float* ebl = inp + (size_t)b * T * K + jo;
    float*       obl = out + (size_t)b * T * K + jo;

    float* a0 = &alpha[0][wv][half][0];
    float* a1 = &alpha[1][wv][half][0];

    {   // t = 0: alpha_0 = emissions_0
        float x = ebl[0];
        a0[j] = x;                         // idle lanes land in pad slots
        if (act) obl[0] = x;
    }
    float e = ebl[K];                      // e(1)
    float f = ebl[2 * K];                  // e(2)

#define FSTEP(AC, AN, E, TT) do {                                             \
    float a_[K];                                                              \
    _Pragma("unroll")                                                         \
    for (int c = 0; c < 6; ++c) {                                             \
        float4 v_ = ((const float4*)(AC))[c];                                 \
        a_[4*c] = v_.x; a_[4*c+1] = v_.y; a_[4*c+2] = v_.z; a_[4*c+3] = v_.w; \
    }                                                                         \
    float u_[8];                                                              \
    _Pragma("unroll")                                                         \
    for (int k = 0; k < 8; ++k)                                               \
        u_[k] = max3f(a_[3*k]   + tc[3*k],                                    \
                      a_[3*k+1] + tc[3*k+1],                                  \
                      a_[3*k+2] + tc[3*k+2]);                                 \
    float w0_ = max3f(u_[0], u_[1], u_[2]);                                   \
    float w1_ = max3f(u_[3], u_[4], u_[5]);                                   \
    float w2_ = fmaxf(u_[6], u_[7]);                                          \
    float o_  = max3f(w0_, w1_, w2_) + (E);                                   \
    (AN)[j] = o_;                                                             \
    if (act) obl[(size_t)(TT) * K] = o_;                                      \
} while (0)

#pragma unroll 1
    for (int it = 0; it < 255; ++it) {
        const int t = 1 + 2 * it;                     // 1,3,...,509
        float gnxt = ebl[(size_t)(t + 2) * K];        // e(t+2), always valid
        FSTEP(a0, a1, e, t);
        int tb = t + 3; tb = tb > 511 ? 511 : tb;
        float hnxt = ebl[(size_t)tb * K];
        FSTEP(a1, a0, f, t + 1);
        e = gnxt; f = hnxt;
    }
    FSTEP(a0, a1, e, 511);                            // t = 511 (final)
#undef FSTEP
}

// ---------------------------------------------------------------------------
// 32-lane-group max reduce, all lanes receive the max. 4 DPP steps (VALU
// latency) + 1 ds_swizzle xor-16. Exact (fmax of finite floats).
// ---------------------------------------------------------------------------
__device__ __forceinline__ float groupmax32(float v) {
    float t;
    t = __int_as_float(__builtin_amdgcn_mov_dpp(__float_as_int(v), 0xB1, 0xF, 0xF, true));   // quad_perm [1,0,3,2]
    v = fmaxf(v, t);
    t = __int_as_float(__builtin_amdgcn_mov_dpp(__float_as_int(v), 0x4E, 0xF, 0xF, true));   // quad_perm [2,3,0,1]
    v = fmaxf(v, t);
    t = __int_as_float(__builtin_amdgcn_mov_dpp(__float_as_int(v), 0x141, 0xF, 0xF, true));  // row_half_mirror
    v = fmaxf(v, t);
    t = __int_as_float(__builtin_amdgcn_mov_dpp(__float_as_int(v), 0x140, 0xF, 0xF, true));  // row_mirror
    v = fmaxf(v, t);
    t = __int_as_float(__builtin_amdgcn_ds_swizzle(__float_as_int(v), 0x401F));              // xor 16
    v = fmaxf(v, t);
    return v;
}

// ---------------------------------------------------------------------------
// Fused backtrack + one-hot. 32 lanes per batch (lane i owns tag-row i),
// 2 batches/wave, 4096 waves. Per step: prefetched alpha_t[i] (8-deep
// rotation) + trans[i][cur] from stride-25 LDS -> DPP value-max ->
// cur = ctz(ballot(s == M)) (exact first-index: float == groups ties, ctz
// picks lowest lane; matches jnp.argmax incl. +/-0) -> coalesced one-hot.
// ---------------------------------------------------------------------------
__global__ __launch_bounds__(256) __attribute__((amdgpu_waves_per_eu(4, 4)))
void crf_backtrack(const float* __restrict__ trans,  // [K, K]
                   float* __restrict__ out)          // [B,T,K] alpha->onehot
{
    __shared__ float tl[K * 25];      // tl[i*25 + j] = trans[i][j]

    const int tid = threadIdx.x;
    for (int idx = tid; idx < K * K; idx += 256) {
        int i = idx / K, j = idx - K * i;
        tl[i * 25 + j] = trans[idx];
    }
    __syncthreads();

    const int lane = tid & 63;
    const int half = lane >> 5;            // batch within wave (0/1)
    const int i    = lane & 31;            // tag row (24..31 idle)
    const int wv   = tid >> 6;
    const int b    = blockIdx.x * 8 + wv * 2 + half;
    const int shmt = half * 32;

    const bool act = (i < K);
    const int  io  = act ? i : (K - 1);

    float* ob = out + (size_t)b * T * K;
    const float* rp  = ob + (size_t)511 * K + io;   // prefetch pointer
    float*       wpp = ob + (size_t)511 * K + io;   // write pointer

    float q[8];                            // slot = t & 7
#pragma unroll
    for (int s = 0; s < 8; ++s) { q[7 - s] = *rp; rp -= K; }   // t=511..504

    int cur;
    {   // t = 511: last_tag = first-index argmax of alpha_511
        float s = act ? q[7] : -INFINITY;
        float M = groupmax32(s);
        uint32_t m32 = (uint32_t)(__ballot(s == M) >> shmt);
        cur = (int)__builtin_ctz(m32);
        if (act) *wpp = (i == cur) ? 1.0f : 0.0f;
        wpp -= K;
        q[7] = *rp; rp -= K;               // prefetch t=503 into slot 7
    }

#define STEP_BT(S, TT) do {                                                   \
    float tv_ = tl[io * 25 + cur];                                            \
    float s_  = act ? (q[S] + tv_) : -INFINITY;                               \
    float M_  = groupmax32(s_);                                               \
    uint32_t m32_ = (uint32_t)(__ballot(s_ == M_) >> shmt);                   \
    cur = (int)__builtin_ctz(m32_);                                           \
    if (act) *wpp = (i == cur) ? 1.0f : 0.0f;                                 \
    wpp -= K;                                                                 \
    if ((TT) >= 8) { q[S] = *rp; rp -= K; }                                   \
} while (0)

#pragma unroll 1
    for (int it = 0; it < 63; ++it) {      // t = 510 .. 7
        const int t0 = 510 - 8 * it;
        STEP_BT(6, t0);     STEP_BT(5, t0 - 1);
        STEP_BT(4, t0 - 2); STEP_BT(3, t0 - 3);
        STEP_BT(2, t0 - 4); STEP_BT(1, t0 - 5);
        STEP_BT(0, t0 - 6); STEP_BT(7, t0 - 7);
    }
    // epilogue: t = 6..0 (all slots already resident)
    STEP_BT(6, 6); STEP_BT(5, 5); STEP_BT(4, 4);
    STEP_BT(3, 3); STEP_BT(2, 2); STEP_BT(1, 1); STEP_BT(0, 0);
#undef STEP_BT
}

extern "C" void kernel_launch(void* const* d_in, const int* in_sizes, int n_in,
                              void* d_out, int out_size, void* d_ws, size_t ws_size,
                              hipStream_t stream) {
    const float* inp   = (const float*)d_in[0];   // [8192, 512, 24]
    const float* trans = (const float*)d_in[1];   // [24, 24]
    float*       out   = (float*)d_out;           // [8192, 512, 24]

    crf_forward<<<B / 8, 256, 0, stream>>>(inp, trans, out);
    crf_backtrack<<<B / 8, 256, 0, stream>>>(trans, out);
}

// Round 10
// 344.018 us; speedup vs baseline: 1.4072x; 1.4072x over previous
//
#include <hip/hip_runtime.h>
#include <stdint.h>

#define B 8192
#define T 512
#define K 24

__device__ __forceinline__ float max3f(float a, float b, float c) {
    return fmaxf(fmaxf(a, b), c);   // fuses to v_max3_f32
}

// ---------------------------------------------------------------------------
// Forward Viterbi, VALUE-ONLY (no backpointers). Round-8 geometry: 64-thread
// block = one wave = 8 batches (8 lanes x 3 contiguous cols each). Alpha
// exchange via LDS within the wave (in-order DS pipe -> no barriers); this
// geometry minimizes LDS-pipe instructions (24/CU/step vs 96 for 2-batch
// waves). NEW vs round 8: emission prefetch deepened to 4-7 steps (unroll x4,
// 4 named register triples) so the ~900-cyc HBM latency never lands on the
// 1-wave/SIMD critical path. Max via v_max3 trees (order-free exact).
// Alpha_t streams into d_out[b][t][:]; backtrack recomputes exact argmax.
// ---------------------------------------------------------------------------
__global__ __launch_bounds__(64) __attribute__((amdgpu_waves_per_eu(1, 1)))
void crf_forward(const float* __restrict__ inp,    // [B, T, K]
                 const float* __restrict__ trans,  // [K, K] (prev i -> cur j)
                 float* __restrict__ out)          // [B, T, K] <- alpha
{
    __shared__ float alpha[2][8][K];

    const int lane = threadIdx.x;          // one wave per block
    const int g    = lane >> 3;            // batch group 0..7
    const int l    = lane & 7;             // lane within group
    const int c0   = 3 * l;                // this lane's columns c0..c0+2
    const int b    = blockIdx.x * 8 + g;   // 1024 blocks * 8 = 8192

    float tc[3][K];                        // 72 regs; waves_per_eu(1,1) budget
#pragma unroll
    for (int j = 0; j < 3; ++j)
#pragma unroll
        for (int i = 0; i < K; ++i) tc[j][i] = trans[i * K + c0 + j];

    const float* ebl = inp + (size_t)b * T * K + c0;
    float*       obl = out + (size_t)b * T * K + c0;

    float* a0 = &alpha[0][g][0];
    float* a1 = &alpha[1][g][0];

    {   // t = 0: alpha_0 = emissions_0 (also stored to out)
        float x0 = ebl[0], x1 = ebl[1], x2 = ebl[2];
        a0[c0] = x0; a0[c0 + 1] = x1; a0[c0 + 2] = x2;
        obl[0] = x0; obl[1] = x1; obl[2] = x2;
    }

    // emission ring: eA..eD hold e(t)..e(t+3) for the current chunk
    float eA0 = ebl[1*K],   eA1 = ebl[1*K+1],   eA2 = ebl[1*K+2];
    float eB0 = ebl[2*K],   eB1 = ebl[2*K+1],   eB2 = ebl[2*K+2];
    float eC0 = ebl[3*K],   eC1 = ebl[3*K+1],   eC2 = ebl[3*K+2];
    float eD0 = ebl[4*K],   eD1 = ebl[4*K+1],   eD2 = ebl[4*K+2];

#define STEP(AC, AN, E0, E1, E2, TT) do {                                     \
    float a_[K];                                                              \
    _Pragma("unroll")                                                         \
    for (int c = 0; c < 6; ++c) {                                             \
        float4 v_ = ((const float4*)(AC))[c];                                 \
        a_[4*c] = v_.x; a_[4*c+1] = v_.y; a_[4*c+2] = v_.z; a_[4*c+3] = v_.w; \
    }                                                                         \
    float r_[3];                                                              \
    _Pragma("unroll")                                                         \
    for (int j = 0; j < 3; ++j) {                                             \
        float u_[8];                                                          \
        _Pragma("unroll")                                                     \
        for (int k = 0; k < 8; ++k)                                           \
            u_[k] = max3f(a_[3*k]   + tc[j][3*k],                             \
                          a_[3*k+1] + tc[j][3*k+1],                           \
                          a_[3*k+2] + tc[j][3*k+2]);                          \
        float w0_ = max3f(u_[0], u_[1], u_[2]);                               \
        float w1_ = max3f(u_[3], u_[4], u_[5]);                               \
        float w2_ = fmaxf(u_[6], u_[7]);                                      \
        r_[j] = max3f(w0_, w1_, w2_);                                         \
    }                                                                         \
    float o0_ = r_[0] + (E0), o1_ = r_[1] + (E1), o2_ = r_[2] + (E2);         \
    (AN)[c0] = o0_; (AN)[c0+1] = o1_; (AN)[c0+2] = o2_;                       \
    float* gp_ = obl + (size_t)(TT) * K;                                      \
    gp_[0] = o0_; gp_[1] = o1_; gp_[2] = o2_;                                 \
} while (0)

#pragma unroll 1
    for (int ch = 0; ch < 127; ++ch) {
        const int t = 1 + 4 * ch;              // 1,5,...,505
        // preload e(t+4..t+7); only t+7 can run past the end (clamped)
        const float* p4 = ebl + (size_t)(t + 4) * K;
        const float* p5 = ebl + (size_t)(t + 5) * K;
        const float* p6 = ebl + (size_t)(t + 6) * K;
        int t7 = t + 7; t7 = t7 > 511 ? 511 : t7;
        const float* p7 = ebl + (size_t)t7 * K;
        float nA0 = p4[0], nA1 = p4[1], nA2 = p4[2];
        float nB0 = p5[0], nB1 = p5[1], nB2 = p5[2];
        float nC0 = p6[0], nC1 = p6[1], nC2 = p6[2];
        float nD0 = p7[0], nD1 = p7[1], nD2 = p7[2];

        STEP(a0, a1, eA0, eA1, eA2, t);
        STEP(a1, a0, eB0, eB1, eB2, t + 1);
        STEP(a0, a1, eC0, eC1, eC2, t + 2);
        STEP(a1, a0, eD0, eD1, eD2, t + 3);

        eA0 = nA0; eA1 = nA1; eA2 = nA2;
        eB0 = nB0; eB1 = nB1; eB2 = nB2;
        eC0 = nC0; eC1 = nC1; eC2 = nC2;
        eD0 = nD0; eD1 = nD1; eD2 = nD2;
    }
    // tail: t = 509, 510, 511 (eA..eC already hold their emissions)
    STEP(a0, a1, eA0, eA1, eA2, 509);
    STEP(a1, a0, eB0, eB1, eB2, 510);
    STEP(a0, a1, eC0, eC1, eC2, 511);
#undef STEP
}

// ---------------------------------------------------------------------------
// 32-lane-group max reduce, all lanes receive the max. 4 DPP steps (VALU
// latency) + 1 ds_swizzle xor-16. Exact (fmax of finite floats).
// ---------------------------------------------------------------------------
__device__ __forceinline__ float groupmax32(float v) {
    float t;
    t = __int_as_float(__builtin_amdgcn_mov_dpp(__float_as_int(v), 0xB1, 0xF, 0xF, true));   // quad_perm [1,0,3,2]
    v = fmaxf(v, t);
    t = __int_as_float(__builtin_amdgcn_mov_dpp(__float_as_int(v), 0x4E, 0xF, 0xF, true));   // quad_perm [2,3,0,1]
    v = fmaxf(v, t);
    t = __int_as_float(__builtin_amdgcn_mov_dpp(__float_as_int(v), 0x141, 0xF, 0xF, true));  // row_half_mirror
    v = fmaxf(v, t);
    t = __int_as_float(__builtin_amdgcn_mov_dpp(__float_as_int(v), 0x140, 0xF, 0xF, true));  // row_mirror
    v = fmaxf(v, t);
    t = __int_as_float(__builtin_amdgcn_ds_swizzle(__float_as_int(v), 0x401F));              // xor 16
    v = fmaxf(v, t);
    return v;
}

// ---------------------------------------------------------------------------
// Fused backtrack + one-hot (unchanged from round 9 — measured ~5.6 TB/s,
// at the HBM floor). 32 lanes per batch, 2 batches/wave, 4096 waves.
// cur = ctz(ballot(s == M)) gives exact first-index argmax.
// ---------------------------------------------------------------------------
__global__ __launch_bounds__(256) __attribute__((amdgpu_waves_per_eu(4, 4)))
void crf_backtrack(const float* __restrict__ trans,  // [K, K]
                   float* __restrict__ out)          // [B,T,K] alpha->onehot
{
    __shared__ float tl[K * 25];      // tl[i*25 + j] = trans[i][j]

    const int tid = threadIdx.x;
    for (int idx = tid; idx < K * K; idx += 256) {
        int i = idx / K, j = idx - K * i;
        tl[i * 25 + j] = trans[idx];
    }
    __syncthreads();

    const int lane = tid & 63;
    const int half = lane >> 5;            // batch within wave (0/1)
    const int i    = lane & 31;            // tag row (24..31 idle)
    const int wv   = tid >> 6;
    const int b    = blockIdx.x * 8 + wv * 2 + half;
    const int shmt = half * 32;

    const bool act = (i < K);
    const int  io  = act ? i : (K - 1);

    float* ob = out + (size_t)b * T * K;
    const float* rp  = ob + (size_t)511 * K + io;   // prefetch pointer
    float*       wpp = ob + (size_t)511 * K + io;   // write pointer

    float q[8];                            // slot = t & 7
#pragma unroll
    for (int s = 0; s < 8; ++s) { q[7 - s] = *rp; rp -= K; }   // t=511..504

    int cur;
    {   // t = 511: last_tag = first-index argmax of alpha_511
        float s = act ? q[7] : -INFINITY;
        float M = groupmax32(s);
        uint32_t m32 = (uint32_t)(__ballot(s == M) >> shmt);
        cur = (int)__builtin_ctz(m32);
        if (act) *wpp = (i == cur) ? 1.0f : 0.0f;
        wpp -= K;
        q[7] = *rp; rp -= K;               // prefetch t=503 into slot 7
    }

#define STEP_BT(S, TT) do {                                                   \
    float tv_ = tl[io * 25 + cur];                                            \
    float s_  = act ? (q[S] + tv_) : -INFINITY;                               \
    float M_  = groupmax32(s_);                                               \
    uint32_t m32_ = (uint32_t)(__ballot(s_ == M_) >> shmt);                   \
    cur = (int)__builtin_ctz(m32_);                                           \
    if (act) *wpp = (i == cur) ? 1.0f : 0.0f;                                 \
    wpp -= K;                                                                 \
    if ((TT) >= 8) { q[S] = *rp; rp -= K; }                                   \
} while (0)

#pragma unroll 1
    for (int it = 0; it < 63; ++it) {      // t = 510 .. 7
        const int t0 = 510 - 8 * it;
        STEP_BT(6, t0);     STEP_BT(5, t0 - 1);
        STEP_BT(4, t0 - 2); STEP_BT(3, t0 - 3);
        STEP_BT(2, t0 - 4); STEP_BT(1, t0 - 5);
        STEP_BT(0, t0 - 6); STEP_BT(7, t0 - 7);
    }
    // epilogue: t = 6..0 (all slots already resident)
    STEP_BT(6, 6); STEP_BT(5, 5); STEP_BT(4, 4);
    STEP_BT(3, 3); STEP_BT(2, 2); STEP_BT(1, 1); STEP_BT(0, 0);
#undef STEP_BT
}

extern "C" void kernel_launch(void* const* d_in, const int* in_sizes, int n_in,
                              void* d_out, int out_size, void* d_ws, size_t ws_size,
                              hipStream_t stream) {
    const float* inp   = (const float*)d_in[0];   // [8192, 512, 24]
    const float* trans = (const float*)d_in[1];   // [24, 24]
    float*       out   = (float*)d_out;           // [8192, 512, 24]

    crf_forward<<<B / 8, 64, 0, stream>>>(inp, trans, out);
    crf_backtrack<<<B / 8, 256, 0, stream>>>(trans, out);
}